// Round 1
// 596.829 us; speedup vs baseline: 1.2123x; 1.2123x over previous
//
#include <hip/hip_runtime.h>
#include <hip/hip_bf16.h>

#define TK 8192
#define HD 1024
#define NE 64
#define TOPK 2
#define CAP 1024
#define FD 512
#define SFD 1024

typedef unsigned short u16;
typedef unsigned int u32;
typedef short bf16x8 __attribute__((ext_vector_type(8)));
typedef float f32x4 __attribute__((ext_vector_type(4)));

#define M_EXP1 0
#define M_EXP2 1
#define M_SH1  2
#define M_SH2  3

__device__ __forceinline__ float bf2f(u16 b){
  u32 u = ((u32)b) << 16;
  return __uint_as_float(u);
}
__device__ __forceinline__ u16 f2bf(float f){
  u32 u = __float_as_uint(f);
  u32 r = (u + 0x7fffu + ((u >> 16) & 1u)) >> 16;
  return (u16)r;
}
__device__ __forceinline__ float gelu_tanh(float x){
  float x3 = x * x * x;
  float t = tanhf(0.7978845608028654f * (x + 0.044715f * x3));
  return 0.5f * x * (1.0f + t);
}

// async global->LDS, 16B per lane; LDS dest = wave-uniform base + lane*16
typedef __attribute__((address_space(1))) const u32 gu32;
typedef __attribute__((address_space(3))) u32 lu32;
__device__ __forceinline__ void gload_lds16(const void* g, void* l){
  gu32* gp = (gu32*)(unsigned long long)(uintptr_t)g;
  lu32* lp = (lu32*)(u32)(uintptr_t)l;
  __builtin_amdgcn_global_load_lds(gp, lp, 16, 0, 0);
}

// ---------------- prep: cast x to bf16 ----------------
__global__ __launch_bounds__(256) void cast_x_kernel(const float* __restrict__ x,
                                                     u16* __restrict__ xbf){
  size_t i = ((size_t)blockIdx.x * 256 + threadIdx.x) * 4;
  float4 v = *(const float4*)&x[i];
  ushort4 o;
  o.x = f2bf(v.x); o.y = f2bf(v.y); o.z = f2bf(v.z); o.w = f2bf(v.w);
  *(ushort4*)&xbf[i] = o;
}

// ---------------- prep: batched transpose fp32 [B,R,C] -> bf16 [B,C,R] ----------------
__global__ __launch_bounds__(256) void transpose_cast(const float* __restrict__ src,
                                                      u16* __restrict__ dst,
                                                      int R, int C){
  __shared__ float tile[64][65];
  const int c0 = blockIdx.x * 64, r0 = blockIdx.y * 64;
  const size_t bb = (size_t)blockIdx.z * R * C;
  const int tid = threadIdx.x;
  const int tr = tid >> 4, tc = (tid & 15) * 4;
#pragma unroll
  for (int i = 0; i < 4; i++){
    float4 v = *(const float4*)&src[bb + (size_t)(r0 + tr + i * 16) * C + c0 + tc];
    tile[tr + i * 16][tc + 0] = v.x;
    tile[tr + i * 16][tc + 1] = v.y;
    tile[tr + i * 16][tc + 2] = v.z;
    tile[tr + i * 16][tc + 3] = v.w;
  }
  __syncthreads();
#pragma unroll
  for (int i = 0; i < 4; i++){
    int dr = tr + i * 16;
    ushort4 o;
    o.x = f2bf(tile[tc + 0][dr]);
    o.y = f2bf(tile[tc + 1][dr]);
    o.z = f2bf(tile[tc + 2][dr]);
    o.w = f2bf(tile[tc + 3][dr]);
    *(ushort4*)&dst[bb + (size_t)(c0 + dr) * R + r0 + tc] = o;
  }
}

// ---------------- router GEMM (fp32, deterministic K-split partials) ----------------
__global__ __launch_bounds__(256) void router_gemm(const float* __restrict__ X,
                                                   const float* __restrict__ Wr,
                                                   float* __restrict__ part){
  __shared__ float Xs[32][36];
  __shared__ float Ws[32][64];
  const int t0 = blockIdx.x * 32;
  const int kh = blockIdx.y;
  const int tid = threadIdx.x;
  const int tx = tid & 15, ty = tid >> 4;
  float acc[2][4] = {};
  for (int k0 = kh * 512; k0 < kh * 512 + 512; k0 += 32){
    {
      int c = tid; int r = c >> 3, cc = (c & 7) * 4;
      *(float4*)&Xs[r][cc] = *(const float4*)&X[(size_t)(t0 + r) * HD + k0 + cc];
    }
#pragma unroll
    for (int i = 0; i < 2; i++){
      int c = tid + i * 256; int r = c >> 4, cc = (c & 15) * 4;
      *(float4*)&Ws[r][cc] = *(const float4*)&Wr[(size_t)(k0 + r) * NE + cc];
    }
    __syncthreads();
#pragma unroll
    for (int kk = 0; kk < 32; kk += 4){
      float a[2][4], b[4][4];
#pragma unroll
      for (int i = 0; i < 2; i++){
        float4 v = *(const float4*)&Xs[ty * 2 + i][kk];
        a[i][0] = v.x; a[i][1] = v.y; a[i][2] = v.z; a[i][3] = v.w;
      }
#pragma unroll
      for (int q = 0; q < 4; q++){
        float4 v = *(const float4*)&Ws[kk + q][tx * 4];
        b[q][0] = v.x; b[q][1] = v.y; b[q][2] = v.z; b[q][3] = v.w;
      }
#pragma unroll
      for (int i = 0; i < 2; i++)
#pragma unroll
        for (int j = 0; j < 4; j++)
          acc[i][j] += a[i][0]*b[0][j] + a[i][1]*b[1][j] + a[i][2]*b[2][j] + a[i][3]*b[3][j];
    }
    __syncthreads();
  }
#pragma unroll
  for (int i = 0; i < 2; i++){
    float4 o; o.x = acc[i][0]; o.y = acc[i][1]; o.z = acc[i][2]; o.w = acc[i][3];
    *(float4*)&part[(size_t)kh * TK * NE + (size_t)(t0 + ty * 2 + i) * NE + tx * 4] = o;
  }
}

// ---------------- routing: one wave per token ----------------
__global__ __launch_bounds__(256) void route_kernel(const float* __restrict__ lp,
    int* __restrict__ cnt, float* __restrict__ Ppart,
    int* __restrict__ assign_row, float* __restrict__ gateA, int* __restrict__ destA,
    u16* __restrict__ Ybuf){
  const int wave = threadIdx.x >> 6, l = threadIdx.x & 63;
  const int t = blockIdx.x * 4 + wave;
  float v = lp[(size_t)t * NE + l] + lp[(size_t)TK * NE + (size_t)t * NE + l];
  float m = v;
#pragma unroll
  for (int s = 32; s; s >>= 1){ float o = __shfl_xor(m, s); m = (o > m) ? o : m; }
  float ex = __expf(v - m);
  float ssum = ex;
#pragma unroll
  for (int s = 32; s; s >>= 1) ssum += __shfl_xor(ssum, s);
  float p = ex / ssum;
  float bv = p; int bi = l;
#pragma unroll
  for (int s = 32; s; s >>= 1){
    float ov = __shfl_xor(bv, s); int oi = __shfl_xor(bi, s);
    if (ov > bv || (ov == bv && oi < bi)){ bv = ov; bi = oi; }
  }
  int e1 = bi; float p1 = bv;
  float pmask = (l == e1) ? -1.f : p;
  bv = pmask; bi = l;
#pragma unroll
  for (int s = 32; s; s >>= 1){
    float ov = __shfl_xor(bv, s); int oi = __shfl_xor(bi, s);
    if (ov > bv || (ov == bv && oi < bi)){ bv = ov; bi = oi; }
  }
  int e2 = bi; float p2 = bv;
  int pos1 = 0, pos2 = 0;
  if (l == 0){
    pos1 = atomicAdd(&cnt[e1], 1);
    pos2 = atomicAdd(&cnt[e2], 1);
    if (pos1 < CAP){ int s1 = e1 * CAP + pos1; assign_row[s1] = t; gateA[s1] = p1; destA[s1] = 2 * t; }
    if (pos2 < CAP){ int s2 = e2 * CAP + pos2; assign_row[s2] = t; gateA[s2] = p2; destA[s2] = 2 * t + 1; }
  }
  pos1 = __shfl(pos1, 0);
  pos2 = __shfl(pos2, 0);
  if (pos1 >= CAP){   // dropped (rare): zero Ybuf row
    bf16x8 z = {0,0,0,0,0,0,0,0};
    *(bf16x8*)&Ybuf[(size_t)(2 * t) * HD + l * 16] = z;
    *(bf16x8*)&Ybuf[(size_t)(2 * t) * HD + l * 16 + 8] = z;
  }
  if (pos2 >= CAP){
    bf16x8 z = {0,0,0,0,0,0,0,0};
    *(bf16x8*)&Ybuf[(size_t)(2 * t + 1) * HD + l * 16] = z;
    *(bf16x8*)&Ybuf[(size_t)(2 * t + 1) * HD + l * 16 + 8] = z;
  }
  __shared__ float sh[4][64];
  sh[wave][l] = p;
  __syncthreads();
  if (wave == 0)
    Ppart[(size_t)blockIdx.x * 64 + l] = sh[0][l] + sh[1][l] + sh[2][l] + sh[3][l];
}

// ---------------- pipelined MFMA GEMM core: 128x128 tile, BK=32,
// 3-buffer LDS, 2-deep prefetch, counted vmcnt, raw barriers ----------------
template<int MODE, int KDIM, int NDIM>
__device__ __forceinline__ void gemm_core(
    u16* SMEM,
    const u16* __restrict__ A, const u16* __restrict__ BT,
    u16* __restrict__ Obuf, float* __restrict__ outF,
    int e, int mbase, int nbase, int count,
    const int* __restrict__ assign_row, const float* __restrict__ gate,
    const int* __restrict__ destIdx, const u16* __restrict__ Ybuf)
{
  const int tid = threadIdx.x;
  const int wave = tid >> 6, lane = tid & 63;
  const int wr = wave & 1, wc = wave >> 1;
  const int lm = lane & 15, quad = lane >> 4;
  const int l4r = lane >> 2;
  const int l4c = (lane & 3) * 8;

  const size_t eoffB = (MODE == M_EXP1 || MODE == M_EXP2) ? (size_t)e * (size_t)NDIM * KDIM : 0;
  const u16* agp[2]; const u16* bgp[2];
  int aoff[2], boff[2];
#pragma unroll
  for (int it = 0; it < 2; it++){
    int ar = wave * 16 + it * 64 + l4r;
    if (MODE == M_EXP1){
      int r = mbase + ar;
      int tok = (r < count) ? assign_row[e * CAP + r] : 0;
      agp[it] = A + (size_t)tok * KDIM + l4c;
    } else if (MODE == M_EXP2){
      agp[it] = A + ((size_t)e * CAP + mbase + ar) * KDIM + l4c;
    } else {
      agp[it] = A + (size_t)(mbase + ar) * KDIM + l4c;
    }
    bgp[it] = BT + eoffB + (size_t)(nbase + ar) * KDIM + l4c;
    aoff[it] = (wave * 16 + it * 64) * 32;
    boff[it] = 4096 + (wave * 16 + it * 64) * 32;
  }

  // stage K-tile t into LDS buffer buf (A: 128x32, B: 128x32)
  auto STAGE = [&](int t, int buf){
    const int ko = t * 32;
    u16* base = SMEM + buf * 8192;
    gload_lds16(agp[0] + ko, base + aoff[0]);
    gload_lds16(agp[1] + ko, base + aoff[1]);
    gload_lds16(bgp[0] + ko, base + boff[0]);
    gload_lds16(bgp[1] + ko, base + boff[1]);
  };

  f32x4 acc[4][4];
#pragma unroll
  for (int mi = 0; mi < 4; mi++)
#pragma unroll
    for (int ni = 0; ni < 4; ni++)
      acc[mi][ni] = (f32x4){0.f, 0.f, 0.f, 0.f};

  constexpr int NT = KDIM / 32;
  // prologue: 2-deep prefetch
  STAGE(0, 0);
  STAGE(1, 1);
  asm volatile("s_waitcnt vmcnt(4)" ::: "memory");   // buf0 ready, buf1 in flight
  __builtin_amdgcn_s_barrier();

  int cur = 0;
  for (int t = 0; t < NT; ++t){
    if (t + 2 < NT){
      int nb = cur + 2; if (nb >= 3) nb -= 3;
      STAGE(t + 2, nb);                              // issue-early: hides under 2 compute phases
    }
    const u16* As_ = SMEM + cur * 8192;
    const u16* Bs_ = As_ + 4096;
    bf16x8 af[4], bfr[4];
#pragma unroll
    for (int mi = 0; mi < 4; mi++)
      af[mi] = *(const bf16x8*)&As_[(wr * 64 + mi * 16 + lm) * 32 + quad * 8];
#pragma unroll
    for (int ni = 0; ni < 4; ni++)
      bfr[ni] = *(const bf16x8*)&Bs_[(wc * 64 + ni * 16 + lm) * 32 + quad * 8];
    asm volatile("s_waitcnt lgkmcnt(0)" ::: "memory");
    __builtin_amdgcn_sched_barrier(0);
    __builtin_amdgcn_s_setprio(1);
#pragma unroll
    for (int mi = 0; mi < 4; mi++)
#pragma unroll
      for (int ni = 0; ni < 4; ni++)
        acc[mi][ni] = __builtin_amdgcn_mfma_f32_16x16x32_bf16(af[mi], bfr[ni], acc[mi][ni], 0, 0, 0);
    __builtin_amdgcn_s_setprio(0);
    if (t + 1 < NT){
      if (t + 2 < NT)
        asm volatile("s_waitcnt vmcnt(4)" ::: "memory");  // next buf ready; newest stage stays in flight
      else
        asm volatile("s_waitcnt vmcnt(0)" ::: "memory");  // tail: drain
      __builtin_amdgcn_s_barrier();
      cur = cur + 1; if (cur >= 3) cur = 0;
    }
  }

#pragma unroll
  for (int mi = 0; mi < 4; mi++){
#pragma unroll
    for (int i = 0; i < 4; i++){
      int r = mbase + wr * 64 + mi * 16 + quad * 4 + i;
      if ((MODE == M_EXP1 || MODE == M_EXP2) && r >= count) continue;
      u16* brow = nullptr;
      float* orow = nullptr;
      const u16 *yb0 = nullptr, *yb1 = nullptr;
      float g = 0.f;
      if (MODE == M_EXP1){
        brow = Obuf + ((size_t)e * CAP + r) * NDIM;
      } else if (MODE == M_EXP2){
        int d = destIdx[e * CAP + r];
        g = gate[e * CAP + r];
        brow = Obuf + (size_t)d * NDIM;
      } else if (MODE == M_SH1){
        brow = Obuf + (size_t)r * NDIM;
      } else {
        orow = outF + (size_t)r * NDIM;
        yb0 = Ybuf + (size_t)(2 * r) * NDIM;
        yb1 = Ybuf + (size_t)(2 * r + 1) * NDIM;
      }
#pragma unroll
      for (int ni = 0; ni < 4; ni++){
        int c = nbase + wc * 64 + ni * 16 + lm;
        float v = acc[mi][ni][i];
        if (MODE == M_EXP1)      brow[c] = f2bf(gelu_tanh(v));
        else if (MODE == M_EXP2) brow[c] = f2bf(g * v);
        else if (MODE == M_SH1)  brow[c] = f2bf(gelu_tanh(v));
        else                     orow[c] = v + bf2f(yb0[c]) + bf2f(yb1[c]);
      }
    }
  }
}

// ---------------- phase A: EXP1 (2048 blocks) + SH1 (512 blocks), fused ----------------
__global__ __launch_bounds__(256) void gemm_phaseA(
    const u16* __restrict__ xbf, const u16* __restrict__ w1T, const u16* __restrict__ ws1T,
    u16* __restrict__ Hbuf, u16* __restrict__ Shb,
    const int* __restrict__ cnt, const int* __restrict__ assign_row)
{
  __shared__ __align__(16) u16 SMEM[3 * 8192];
  const int bid = blockIdx.x;
  if (bid < 2048){
    // EXP1: bijective XCD-chunk swizzle over 2048 (8 experts/XCD), n-fastest
    int logical = (bid & 7) * 256 + (bid >> 3);
    int e = logical >> 5, r = logical & 31;
    int mbase = (r >> 2) * 128, nbase = (r & 3) * 128;
    int count = cnt[e];
    if (mbase >= count) return;
    gemm_core<M_EXP1, HD, FD>(SMEM, xbf, w1T, Hbuf, nullptr, e, mbase, nbase, count,
                              assign_row, nullptr, nullptr, nullptr);
  } else {
    // SH1: swizzle over 512 (64 m-tiles, 8 n-tiles), n-fastest
    int b2 = bid - 2048;                 // 2048 % 8 == 0, so b2 & 7 still tracks XCD
    int logical = (b2 & 7) * 64 + (b2 >> 3);
    int mbase = (logical >> 3) * 128, nbase = (logical & 7) * 128;
    gemm_core<M_SH1, HD, SFD>(SMEM, xbf, ws1T, Shb, nullptr, 0, mbase, nbase, 0,
                              nullptr, nullptr, nullptr, nullptr);
  }
}

// ---------------- phase B: EXP2 (4096 blocks) ----------------
__global__ __launch_bounds__(256) void gemm_exp2(
    const u16* __restrict__ Hbuf, const u16* __restrict__ w2T, u16* __restrict__ Ybuf,
    const int* __restrict__ cnt, const float* __restrict__ gateA, const int* __restrict__ destA)
{
  __shared__ __align__(16) u16 SMEM[3 * 8192];
  const int bid = blockIdx.x;
  int logical = (bid & 7) * 512 + (bid >> 3);
  int e = logical >> 6, r = logical & 63;
  int mbase = (r >> 3) * 128, nbase = (r & 7) * 128;
  int count = cnt[e];
  if (mbase >= count) return;
  gemm_core<M_EXP2, FD, HD>(SMEM, Hbuf, w2T, Ybuf, nullptr, e, mbase, nbase, count,
                            nullptr, gateA, destA, nullptr);
}

// ---------------- phase C: SH2 + combine (512 blocks) ----------------
__global__ __launch_bounds__(256) void gemm_sh2(
    const u16* __restrict__ Shb, const u16* __restrict__ ws2T,
    float* __restrict__ outF, const u16* __restrict__ Ybuf)
{
  __shared__ __align__(16) u16 SMEM[3 * 8192];
  const int bid = blockIdx.x;
  int logical = (bid & 7) * 64 + (bid >> 3);
  int mbase = (logical >> 3) * 128, nbase = (logical & 7) * 128;
  gemm_core<M_SH2, SFD, HD>(SMEM, Shb, ws2T, nullptr, outF, 0, mbase, nbase, 0,
                            nullptr, nullptr, nullptr, Ybuf);
}

// ---------------- aux stage 1: reduce Ppart[2048][64] -> P1[64][64] ----------------
__global__ __launch_bounds__(256) void aux1_kernel(const float* __restrict__ Ppart,
                                                   float* __restrict__ P1){
  const int l = threadIdx.x & 63, w = threadIdx.x >> 6;
  const int r0 = blockIdx.x * 32;
  float s = 0.f;
#pragma unroll
  for (int j = 0; j < 8; j++)
    s += Ppart[(size_t)(r0 + w + 4 * j) * 64 + l];
  __shared__ float sh[4][64];
  sh[w][l] = s;
  __syncthreads();
  if (w == 0)
    P1[(size_t)blockIdx.x * 64 + l] = sh[0][l] + sh[1][l] + sh[2][l] + sh[3][l];
}

// ---------------- aux stage 2: reduce P1[64][64], emit loss ----------------
__global__ __launch_bounds__(256) void aux2_kernel(const int* __restrict__ cnt,
    const float* __restrict__ P1, float* __restrict__ out){
  const int l = threadIdx.x & 63, w = threadIdx.x >> 6;
  float s = 0.f;
#pragma unroll
  for (int j = 0; j < 16; j++)
    s += P1[(size_t)(w + 4 * j) * 64 + l];
  __shared__ float sh[4][64];
  sh[w][l] = s;
  __syncthreads();
  if (w == 0){
    float P = (sh[0][l] + sh[1][l] + sh[2][l] + sh[3][l]) * (1.0f / (float)TK);
    float f = (float)cnt[l] * (1.0f / (float)(TK * TOPK));
    float v = f * P;
#pragma unroll
    for (int s2 = 32; s2; s2 >>= 1) v += __shfl_xor(v, s2);
    if (l == 0) out[(size_t)TK * HD] = 0.64f * v;   // COEFF * E = 0.01 * 64
  }
}

extern "C" void kernel_launch(void* const* d_in, const int* in_sizes, int n_in,
                              void* d_out, int out_size, void* d_ws, size_t ws_size,
                              hipStream_t stream){
  const float* x   = (const float*)d_in[0];
  const float* wr  = (const float*)d_in[1];
  const float* w1  = (const float*)d_in[2];
  const float* w2  = (const float*)d_in[3];
  const float* ws1 = (const float*)d_in[4];
  const float* ws2 = (const float*)d_in[5];
  float* out = (float*)d_out;

  char* W = (char*)d_ws;
  size_t off = 0;
  auto alloc = [&](size_t b){ size_t o = off; off = (off + b + 255) & ~(size_t)255; return o; };
  u16*   xbf   = (u16*)(W + alloc((size_t)TK * HD * 2));
  u16*   w1T   = (u16*)(W + alloc((size_t)NE * FD * HD * 2));
  u16*   w2T   = (u16*)(W + alloc((size_t)NE * HD * FD * 2));
  u16*   ws1T  = (u16*)(W + alloc((size_t)HD * SFD * 2));
  u16*   ws2T  = (u16*)(W + alloc((size_t)SFD * HD * 2));
  u16*   Hbuf  = (u16*)(W + alloc((size_t)NE * CAP * FD * 2));
  u16*   Shb   = (u16*)(W + alloc((size_t)TK * SFD * 2));
  u16*   Ybuf  = (u16*)(W + alloc((size_t)TK * TOPK * HD * 2));
  float* lpart = (float*)(W + alloc((size_t)2 * TK * NE * 4));
  int*   assign_row = (int*)(W + alloc((size_t)NE * CAP * 4));
  float* gateA = (float*)(W + alloc((size_t)NE * CAP * 4));
  int*   destA = (int*)(W + alloc((size_t)NE * CAP * 4));
  float* Ppart = (float*)(W + alloc((size_t)(TK / 4) * 64 * 4));
  float* P1    = (float*)(W + alloc((size_t)64 * 64 * 4));
  int*   cnt   = (int*)(W + alloc(256));

  hipMemsetAsync(cnt, 0, 256, stream);

  cast_x_kernel<<<dim3((TK * HD) / 1024), 256, 0, stream>>>(x, xbf);
  transpose_cast<<<dim3(FD / 64, HD / 64, NE), 256, 0, stream>>>(w1, w1T, HD, FD);
  transpose_cast<<<dim3(HD / 64, FD / 64, NE), 256, 0, stream>>>(w2, w2T, FD, HD);
  transpose_cast<<<dim3(SFD / 64, HD / 64, 1), 256, 0, stream>>>(ws1, ws1T, HD, SFD);
  transpose_cast<<<dim3(HD / 64, SFD / 64, 1), 256, 0, stream>>>(ws2, ws2T, SFD, HD);

  router_gemm<<<dim3(TK / 32, 2), 256, 0, stream>>>(x, wr, lpart);
  route_kernel<<<dim3(TK / 4), 256, 0, stream>>>(lpart, cnt, Ppart, assign_row, gateA, destA, Ybuf);

  gemm_phaseA<<<dim3(2048 + 512), 256, 0, stream>>>(xbf, w1T, ws1T, Hbuf, Shb, cnt, assign_row);
  gemm_exp2<<<dim3(4096), 256, 0, stream>>>(Hbuf, w2T, Ybuf, cnt, gateA, destA);
  gemm_sh2<<<dim3(512), 256, 0, stream>>>(Shb, ws2T, out, Ybuf);

  aux1_kernel<<<dim3(64), 256, 0, stream>>>(Ppart, P1);
  aux2_kernel<<<dim3(1), 256, 0, stream>>>(cnt, P1, out);
}

// Round 2
// 537.666 us; speedup vs baseline: 1.3457x; 1.1100x over previous
//
#include <hip/hip_runtime.h>
#include <hip/hip_bf16.h>

#define TK 8192
#define HD 1024
#define NE 64
#define TOPK 2
#define CAP 1024
#define FD 512
#define SFD 1024
#define CNTS 32   // cnt stride in ints -> 128B per expert counter (one cache line each)

typedef unsigned short u16;
typedef unsigned int u32;
typedef short bf16x8 __attribute__((ext_vector_type(8)));
typedef float f32x4 __attribute__((ext_vector_type(4)));

#define M_EXP1 0
#define M_EXP2 1
#define M_SH1  2
#define M_SH2  3

__device__ __forceinline__ float bf2f(u16 b){
  u32 u = ((u32)b) << 16;
  return __uint_as_float(u);
}
__device__ __forceinline__ u16 f2bf(float f){
  u32 u = __float_as_uint(f);
  u32 r = (u + 0x7fffu + ((u >> 16) & 1u)) >> 16;
  return (u16)r;
}
__device__ __forceinline__ float gelu_tanh(float x){
  float x3 = x * x * x;
  float t = tanhf(0.7978845608028654f * (x + 0.044715f * x3));
  return 0.5f * x * (1.0f + t);
}

// async global->LDS, 16B per lane; LDS dest = wave-uniform base + lane*16
typedef __attribute__((address_space(1))) const u32 gu32;
typedef __attribute__((address_space(3))) u32 lu32;
__device__ __forceinline__ void gload_lds16(const void* g, void* l){
  gu32* gp = (gu32*)(unsigned long long)(uintptr_t)g;
  lu32* lp = (lu32*)(u32)(uintptr_t)l;
  __builtin_amdgcn_global_load_lds(gp, lp, 16, 0, 0);
}

// ---------------- prep: cast x to bf16 ----------------
__global__ __launch_bounds__(256) void cast_x_kernel(const float* __restrict__ x,
                                                     u16* __restrict__ xbf){
  size_t i = ((size_t)blockIdx.x * 256 + threadIdx.x) * 4;
  float4 v = *(const float4*)&x[i];
  ushort4 o;
  o.x = f2bf(v.x); o.y = f2bf(v.y); o.z = f2bf(v.z); o.w = f2bf(v.w);
  *(ushort4*)&xbf[i] = o;
}

// ---------------- prep: batched transpose fp32 [B,R,C] -> bf16 [B,C,R] ----------------
__global__ __launch_bounds__(256) void transpose_cast(const float* __restrict__ src,
                                                      u16* __restrict__ dst,
                                                      int R, int C){
  __shared__ float tile[64][65];
  const int c0 = blockIdx.x * 64, r0 = blockIdx.y * 64;
  const size_t bb = (size_t)blockIdx.z * R * C;
  const int tid = threadIdx.x;
  const int tr = tid >> 4, tc = (tid & 15) * 4;
#pragma unroll
  for (int i = 0; i < 4; i++){
    float4 v = *(const float4*)&src[bb + (size_t)(r0 + tr + i * 16) * C + c0 + tc];
    tile[tr + i * 16][tc + 0] = v.x;
    tile[tr + i * 16][tc + 1] = v.y;
    tile[tr + i * 16][tc + 2] = v.z;
    tile[tr + i * 16][tc + 3] = v.w;
  }
  __syncthreads();
#pragma unroll
  for (int i = 0; i < 4; i++){
    int dr = tr + i * 16;
    ushort4 o;
    o.x = f2bf(tile[tc + 0][dr]);
    o.y = f2bf(tile[tc + 1][dr]);
    o.z = f2bf(tile[tc + 2][dr]);
    o.w = f2bf(tile[tc + 3][dr]);
    *(ushort4*)&dst[bb + (size_t)(c0 + dr) * R + r0 + tc] = o;
  }
}

// ---------------- router GEMM (fp32, deterministic K-split partials) ----------------
__global__ __launch_bounds__(256) void router_gemm(const float* __restrict__ X,
                                                   const float* __restrict__ Wr,
                                                   float* __restrict__ part){
  __shared__ float Xs[32][36];
  __shared__ float Ws[32][64];
  const int t0 = blockIdx.x * 32;
  const int kh = blockIdx.y;
  const int tid = threadIdx.x;
  const int tx = tid & 15, ty = tid >> 4;
  float acc[2][4] = {};
  for (int k0 = kh * 512; k0 < kh * 512 + 512; k0 += 32){
    {
      int c = tid; int r = c >> 3, cc = (c & 7) * 4;
      *(float4*)&Xs[r][cc] = *(const float4*)&X[(size_t)(t0 + r) * HD + k0 + cc];
    }
#pragma unroll
    for (int i = 0; i < 2; i++){
      int c = tid + i * 256; int r = c >> 4, cc = (c & 15) * 4;
      *(float4*)&Ws[r][cc] = *(const float4*)&Wr[(size_t)(k0 + r) * NE + cc];
    }
    __syncthreads();
#pragma unroll
    for (int kk = 0; kk < 32; kk += 4){
      float a[2][4], b[4][4];
#pragma unroll
      for (int i = 0; i < 2; i++){
        float4 v = *(const float4*)&Xs[ty * 2 + i][kk];
        a[i][0] = v.x; a[i][1] = v.y; a[i][2] = v.z; a[i][3] = v.w;
      }
#pragma unroll
      for (int q = 0; q < 4; q++){
        float4 v = *(const float4*)&Ws[kk + q][tx * 4];
        b[q][0] = v.x; b[q][1] = v.y; b[q][2] = v.z; b[q][3] = v.w;
      }
#pragma unroll
      for (int i = 0; i < 2; i++)
#pragma unroll
        for (int j = 0; j < 4; j++)
          acc[i][j] += a[i][0]*b[0][j] + a[i][1]*b[1][j] + a[i][2]*b[2][j] + a[i][3]*b[3][j];
    }
    __syncthreads();
  }
#pragma unroll
  for (int i = 0; i < 2; i++){
    float4 o; o.x = acc[i][0]; o.y = acc[i][1]; o.z = acc[i][2]; o.w = acc[i][3];
    *(float4*)&part[(size_t)kh * TK * NE + (size_t)(t0 + ty * 2 + i) * NE + tx * 4] = o;
  }
}

// ---------------- routing: 32 tokens/block, LDS histogram, 1 global atomic per (block,expert) ----------------
__global__ __launch_bounds__(256) void route_kernel(const float* __restrict__ lp,
    int* __restrict__ cnt, float* __restrict__ Ppart,
    int* __restrict__ assign_row, float* __restrict__ gateA, int* __restrict__ destA,
    u16* __restrict__ Ybuf){
  const int wave = threadIdx.x >> 6, l = threadIdx.x & 63;
  const int tid = threadIdx.x;
  __shared__ int lhist[64];
  __shared__ int s_e[64];
  __shared__ int s_lpos[64];
  __shared__ float s_p[64];
  __shared__ float s_ps[4][64];
  __shared__ int s_base[64];
  if (tid < 64) lhist[tid] = 0;
  __syncthreads();

  const int t0 = blockIdx.x * 32 + wave * 8;
  float psum = 0.f;
  // prefetch token 0
  float va = lp[(size_t)t0 * NE + l];
  float vb = lp[(size_t)TK * NE + (size_t)t0 * NE + l];
  for (int i = 0; i < 8; i++){
    float v = va + vb;
    if (i < 7){   // prefetch next token while reducing current
      va = lp[(size_t)(t0 + i + 1) * NE + l];
      vb = lp[(size_t)TK * NE + (size_t)(t0 + i + 1) * NE + l];
    }
    float m = v;
#pragma unroll
    for (int s = 32; s; s >>= 1){ float o = __shfl_xor(m, s); m = (o > m) ? o : m; }
    float ex = __expf(v - m);
    float ssum = ex;
#pragma unroll
    for (int s = 32; s; s >>= 1) ssum += __shfl_xor(ssum, s);
    float p = ex / ssum;
    psum += p;
    float bv = p; int bi = l;
#pragma unroll
    for (int s = 32; s; s >>= 1){
      float ov = __shfl_xor(bv, s); int oi = __shfl_xor(bi, s);
      if (ov > bv || (ov == bv && oi < bi)){ bv = ov; bi = oi; }
    }
    int e1 = bi; float p1 = bv;
    float pmask = (l == e1) ? -1.f : p;
    bv = pmask; bi = l;
#pragma unroll
    for (int s = 32; s; s >>= 1){
      float ov = __shfl_xor(bv, s); int oi = __shfl_xor(bi, s);
      if (ov > bv || (ov == bv && oi < bi)){ bv = ov; bi = oi; }
    }
    int e2 = bi; float p2 = bv;
    if (l == 0){
      int lp1 = atomicAdd(&lhist[e1], 1);
      int lp2 = atomicAdd(&lhist[e2], 1);
      int aid = (wave * 8 + i) * 2;
      s_e[aid] = e1; s_lpos[aid] = lp1; s_p[aid] = p1;
      s_e[aid + 1] = e2; s_lpos[aid + 1] = lp2; s_p[aid + 1] = p2;
    }
  }
  s_ps[wave][l] = psum;
  __syncthreads();
  if (tid < 64)
    s_base[tid] = atomicAdd(&cnt[tid * CNTS], lhist[tid]);
  if (wave == 0)
    Ppart[(size_t)blockIdx.x * 64 + l] = s_ps[0][l] + s_ps[1][l] + s_ps[2][l] + s_ps[3][l];
  __syncthreads();
  if (tid < 64){
    int aid = tid;
    int e = s_e[aid];
    int pos = s_base[e] + s_lpos[aid];
    int t = blockIdx.x * 32 + (aid >> 1);
    int dest = 2 * t + (aid & 1);
    if (pos < CAP){
      int s1 = e * CAP + pos;
      assign_row[s1] = t; gateA[s1] = s_p[aid]; destA[s1] = dest;
    } else {
      // dropped (never at CAP=4x mean load): zero the Ybuf row so SH2's combine reads 0
      for (int j = 0; j < HD; j += 8){
        bf16x8 z = {0,0,0,0,0,0,0,0};
        *(bf16x8*)&Ybuf[(size_t)dest * HD + j] = z;
      }
    }
  }
}

// ---------------- pipelined MFMA GEMM core: 128x128 tile, BK=32,
// 3-buffer LDS, 2-deep prefetch, counted vmcnt, raw barriers ----------------
template<int MODE, int KDIM, int NDIM>
__device__ __forceinline__ void gemm_core(
    u16* SMEM,
    const u16* __restrict__ A, const u16* __restrict__ BT,
    u16* __restrict__ Obuf, float* __restrict__ outF,
    int e, int mbase, int nbase, int count,
    const int* __restrict__ assign_row, const float* __restrict__ gate,
    const int* __restrict__ destIdx, const u16* __restrict__ Ybuf)
{
  const int tid = threadIdx.x;
  const int wave = tid >> 6, lane = tid & 63;
  const int wr = wave & 1, wc = wave >> 1;
  const int lm = lane & 15, quad = lane >> 4;
  const int l4r = lane >> 2;
  const int l4c = (lane & 3) * 8;

  const size_t eoffB = (MODE == M_EXP1 || MODE == M_EXP2) ? (size_t)e * (size_t)NDIM * KDIM : 0;
  const u16* agp[2]; const u16* bgp[2];
  int aoff[2], boff[2];
#pragma unroll
  for (int it = 0; it < 2; it++){
    int ar = wave * 16 + it * 64 + l4r;
    if (MODE == M_EXP1){
      int r = mbase + ar;
      int tok = (r < count) ? assign_row[e * CAP + r] : 0;
      agp[it] = A + (size_t)tok * KDIM + l4c;
    } else if (MODE == M_EXP2){
      agp[it] = A + ((size_t)e * CAP + mbase + ar) * KDIM + l4c;
    } else {
      agp[it] = A + (size_t)(mbase + ar) * KDIM + l4c;
    }
    bgp[it] = BT + eoffB + (size_t)(nbase + ar) * KDIM + l4c;
    aoff[it] = (wave * 16 + it * 64) * 32;
    boff[it] = 4096 + (wave * 16 + it * 64) * 32;
  }

  // stage K-tile t into LDS buffer buf (A: 128x32, B: 128x32)
  auto STAGE = [&](int t, int buf){
    const int ko = t * 32;
    u16* base = SMEM + buf * 8192;
    gload_lds16(agp[0] + ko, base + aoff[0]);
    gload_lds16(agp[1] + ko, base + aoff[1]);
    gload_lds16(bgp[0] + ko, base + boff[0]);
    gload_lds16(bgp[1] + ko, base + boff[1]);
  };

  f32x4 acc[4][4];
#pragma unroll
  for (int mi = 0; mi < 4; mi++)
#pragma unroll
    for (int ni = 0; ni < 4; ni++)
      acc[mi][ni] = (f32x4){0.f, 0.f, 0.f, 0.f};

  constexpr int NT = KDIM / 32;
  // prologue: 2-deep prefetch
  STAGE(0, 0);
  STAGE(1, 1);
  asm volatile("s_waitcnt vmcnt(4)" ::: "memory");   // buf0 ready, buf1 in flight
  __builtin_amdgcn_s_barrier();

  int cur = 0;
  for (int t = 0; t < NT; ++t){
    if (t + 2 < NT){
      int nb = cur + 2; if (nb >= 3) nb -= 3;
      STAGE(t + 2, nb);                              // issue-early: hides under 2 compute phases
    }
    const u16* As_ = SMEM + cur * 8192;
    const u16* Bs_ = As_ + 4096;
    bf16x8 af[4], bfr[4];
#pragma unroll
    for (int mi = 0; mi < 4; mi++)
      af[mi] = *(const bf16x8*)&As_[(wr * 64 + mi * 16 + lm) * 32 + quad * 8];
#pragma unroll
    for (int ni = 0; ni < 4; ni++)
      bfr[ni] = *(const bf16x8*)&Bs_[(wc * 64 + ni * 16 + lm) * 32 + quad * 8];
    asm volatile("s_waitcnt lgkmcnt(0)" ::: "memory");
    __builtin_amdgcn_sched_barrier(0);
    __builtin_amdgcn_s_setprio(1);
#pragma unroll
    for (int mi = 0; mi < 4; mi++)
#pragma unroll
      for (int ni = 0; ni < 4; ni++)
        acc[mi][ni] = __builtin_amdgcn_mfma_f32_16x16x32_bf16(af[mi], bfr[ni], acc[mi][ni], 0, 0, 0);
    __builtin_amdgcn_s_setprio(0);
    if (t + 1 < NT){
      if (t + 2 < NT)
        asm volatile("s_waitcnt vmcnt(4)" ::: "memory");  // next buf ready; newest stage stays in flight
      else
        asm volatile("s_waitcnt vmcnt(0)" ::: "memory");  // tail: drain
      __builtin_amdgcn_s_barrier();
      cur = cur + 1; if (cur >= 3) cur = 0;
    }
  }

#pragma unroll
  for (int mi = 0; mi < 4; mi++){
#pragma unroll
    for (int i = 0; i < 4; i++){
      int r = mbase + wr * 64 + mi * 16 + quad * 4 + i;
      if ((MODE == M_EXP1 || MODE == M_EXP2) && r >= count) continue;
      u16* brow = nullptr;
      float* orow = nullptr;
      const u16 *yb0 = nullptr, *yb1 = nullptr;
      float g = 0.f;
      if (MODE == M_EXP1){
        brow = Obuf + ((size_t)e * CAP + r) * NDIM;
      } else if (MODE == M_EXP2){
        int d = destIdx[e * CAP + r];
        g = gate[e * CAP + r];
        brow = Obuf + (size_t)d * NDIM;
      } else if (MODE == M_SH1){
        brow = Obuf + (size_t)r * NDIM;
      } else {
        orow = outF + (size_t)r * NDIM;
        yb0 = Ybuf + (size_t)(2 * r) * NDIM;
        yb1 = Ybuf + (size_t)(2 * r + 1) * NDIM;
      }
#pragma unroll
      for (int ni = 0; ni < 4; ni++){
        int c = nbase + wc * 64 + ni * 16 + lm;
        float v = acc[mi][ni][i];
        if (MODE == M_EXP1)      brow[c] = f2bf(gelu_tanh(v));
        else if (MODE == M_EXP2) brow[c] = f2bf(g * v);
        else if (MODE == M_SH1)  brow[c] = f2bf(gelu_tanh(v));
        else                     orow[c] = v + bf2f(yb0[c]) + bf2f(yb1[c]);
      }
    }
  }
}

// ---------------- phase A: EXP1 (2048 blocks) + SH1 (512 blocks), fused ----------------
__global__ __launch_bounds__(256) void gemm_phaseA(
    const u16* __restrict__ xbf, const u16* __restrict__ w1T, const u16* __restrict__ ws1T,
    u16* __restrict__ Hbuf, u16* __restrict__ Shb,
    const int* __restrict__ cnt, const int* __restrict__ assign_row)
{
  __shared__ __align__(16) u16 SMEM[3 * 8192];
  const int bid = blockIdx.x;
  if (bid < 2048){
    // EXP1: bijective XCD-chunk swizzle over 2048 (8 experts/XCD), n-fastest
    int logical = (bid & 7) * 256 + (bid >> 3);
    int e = logical >> 5, r = logical & 31;
    int mbase = (r >> 2) * 128, nbase = (r & 3) * 128;
    int count = cnt[e * CNTS];
    if (mbase >= count) return;
    gemm_core<M_EXP1, HD, FD>(SMEM, xbf, w1T, Hbuf, nullptr, e, mbase, nbase, count,
                              assign_row, nullptr, nullptr, nullptr);
  } else {
    // SH1: swizzle over 512 (64 m-tiles, 8 n-tiles), n-fastest
    int b2 = bid - 2048;                 // 2048 % 8 == 0, so b2 & 7 still tracks XCD
    int logical = (b2 & 7) * 64 + (b2 >> 3);
    int mbase = (logical >> 3) * 128, nbase = (logical & 7) * 128;
    gemm_core<M_SH1, HD, SFD>(SMEM, xbf, ws1T, Shb, nullptr, 0, mbase, nbase, 0,
                              nullptr, nullptr, nullptr, nullptr);
  }
}

// ---------------- phase B: EXP2 (4096 blocks) ----------------
__global__ __launch_bounds__(256) void gemm_exp2(
    const u16* __restrict__ Hbuf, const u16* __restrict__ w2T, u16* __restrict__ Ybuf,
    const int* __restrict__ cnt, const float* __restrict__ gateA, const int* __restrict__ destA)
{
  __shared__ __align__(16) u16 SMEM[3 * 8192];
  const int bid = blockIdx.x;
  int logical = (bid & 7) * 512 + (bid >> 3);
  int e = logical >> 6, r = logical & 63;
  int mbase = (r >> 3) * 128, nbase = (r & 7) * 128;
  int count = cnt[e * CNTS];
  if (mbase >= count) return;
  gemm_core<M_EXP2, FD, HD>(SMEM, Hbuf, w2T, Ybuf, nullptr, e, mbase, nbase, count,
                            nullptr, gateA, destA, nullptr);
}

// ---------------- phase C: SH2 + combine (512 blocks) ----------------
__global__ __launch_bounds__(256) void gemm_sh2(
    const u16* __restrict__ Shb, const u16* __restrict__ ws2T,
    float* __restrict__ outF, const u16* __restrict__ Ybuf)
{
  __shared__ __align__(16) u16 SMEM[3 * 8192];
  const int bid = blockIdx.x;
  int logical = (bid & 7) * 64 + (bid >> 3);
  int mbase = (logical >> 3) * 128, nbase = (logical & 7) * 128;
  gemm_core<M_SH2, SFD, HD>(SMEM, Shb, ws2T, nullptr, outF, 0, mbase, nbase, 0,
                            nullptr, nullptr, nullptr, Ybuf);
}

// ---------------- aux: reduce Ppart[256][64] + cnt -> loss ----------------
__global__ __launch_bounds__(256) void aux_kernel(const int* __restrict__ cnt,
    const float* __restrict__ Ppart, float* __restrict__ out){
  const int l = threadIdx.x & 63, w = threadIdx.x >> 6;
  float s = 0.f;
#pragma unroll 4
  for (int j = 0; j < 64; j++)
    s += Ppart[(size_t)(w + 4 * j) * 64 + l];
  __shared__ float sh[4][64];
  sh[w][l] = s;
  __syncthreads();
  if (w == 0){
    float P = (sh[0][l] + sh[1][l] + sh[2][l] + sh[3][l]) * (1.0f / (float)TK);
    float f = (float)cnt[l * CNTS] * (1.0f / (float)(TK * TOPK));
    float v = f * P;
#pragma unroll
    for (int s2 = 32; s2; s2 >>= 1) v += __shfl_xor(v, s2);
    if (l == 0) out[(size_t)TK * HD] = 0.64f * v;   // COEFF * E = 0.01 * 64
  }
}

extern "C" void kernel_launch(void* const* d_in, const int* in_sizes, int n_in,
                              void* d_out, int out_size, void* d_ws, size_t ws_size,
                              hipStream_t stream){
  const float* x   = (const float*)d_in[0];
  const float* wr  = (const float*)d_in[1];
  const float* w1  = (const float*)d_in[2];
  const float* w2  = (const float*)d_in[3];
  const float* ws1 = (const float*)d_in[4];
  const float* ws2 = (const float*)d_in[5];
  float* out = (float*)d_out;

  char* W = (char*)d_ws;
  size_t off = 0;
  auto alloc = [&](size_t b){ size_t o = off; off = (off + b + 255) & ~(size_t)255; return o; };
  u16*   xbf   = (u16*)(W + alloc((size_t)TK * HD * 2));
  u16*   w1T   = (u16*)(W + alloc((size_t)NE * FD * HD * 2));
  u16*   w2T   = (u16*)(W + alloc((size_t)NE * HD * FD * 2));
  u16*   ws1T  = (u16*)(W + alloc((size_t)HD * SFD * 2));
  u16*   ws2T  = (u16*)(W + alloc((size_t)SFD * HD * 2));
  u16*   Hbuf  = (u16*)(W + alloc((size_t)NE * CAP * FD * 2));
  u16*   Shb   = (u16*)(W + alloc((size_t)TK * SFD * 2));
  u16*   Ybuf  = (u16*)(W + alloc((size_t)TK * TOPK * HD * 2));
  float* lpart = (float*)(W + alloc((size_t)2 * TK * NE * 4));
  int*   assign_row = (int*)(W + alloc((size_t)NE * CAP * 4));
  float* gateA = (float*)(W + alloc((size_t)NE * CAP * 4));
  int*   destA = (int*)(W + alloc((size_t)NE * CAP * 4));
  float* Ppart = (float*)(W + alloc((size_t)256 * 64 * 4));
  int*   cnt   = (int*)(W + alloc((size_t)NE * CNTS * 4));

  hipMemsetAsync(cnt, 0, (size_t)NE * CNTS * 4, stream);

  cast_x_kernel<<<dim3((TK * HD) / 1024), 256, 0, stream>>>(x, xbf);
  transpose_cast<<<dim3(FD / 64, HD / 64, NE), 256, 0, stream>>>(w1, w1T, HD, FD);
  transpose_cast<<<dim3(HD / 64, FD / 64, NE), 256, 0, stream>>>(w2, w2T, FD, HD);
  transpose_cast<<<dim3(SFD / 64, HD / 64, 1), 256, 0, stream>>>(ws1, ws1T, HD, SFD);
  transpose_cast<<<dim3(HD / 64, SFD / 64, 1), 256, 0, stream>>>(ws2, ws2T, SFD, HD);

  router_gemm<<<dim3(TK / 32, 2), 256, 0, stream>>>(x, wr, lpart);
  route_kernel<<<dim3(TK / 32), 256, 0, stream>>>(lpart, cnt, Ppart, assign_row, gateA, destA, Ybuf);

  gemm_phaseA<<<dim3(2048 + 512), 256, 0, stream>>>(xbf, w1T, ws1T, Hbuf, Shb, cnt, assign_row);
  gemm_exp2<<<dim3(4096), 256, 0, stream>>>(Hbuf, w2T, Ybuf, cnt, gateA, destA);
  gemm_sh2<<<dim3(512), 256, 0, stream>>>(Shb, ws2T, out, Ybuf);

  aux_kernel<<<dim3(1), 256, 0, stream>>>(cnt, Ppart, out);
}

// Round 3
// 525.188 us; speedup vs baseline: 1.3776x; 1.0238x over previous
//
#include <hip/hip_runtime.h>
#include <hip/hip_bf16.h>

#define TK 8192
#define HD 1024
#define NE 64
#define TOPK 2
#define CAP 1024
#define FD 512
#define SFD 1024
#define CNTS 32   // cnt stride in ints -> 128B per expert counter (one cache line each)

typedef unsigned short u16;
typedef unsigned int u32;
typedef short bf16x8 __attribute__((ext_vector_type(8)));
typedef float f32x4 __attribute__((ext_vector_type(4)));

#define M_EXP1 0
#define M_EXP2 1
#define M_SH1  2
#define M_SH2  3

__device__ __forceinline__ float bf2f(u16 b){
  u32 u = ((u32)b) << 16;
  return __uint_as_float(u);
}
__device__ __forceinline__ u16 f2bf(float f){
  u32 u = __float_as_uint(f);
  u32 r = (u + 0x7fffu + ((u >> 16) & 1u)) >> 16;
  return (u16)r;
}
// gelu tanh-approx: 0.5x(1+tanh(u)) == x * sigmoid(2u), u = 0.79788456*(x+0.044715x^3)
__device__ __forceinline__ float gelu_tanh(float x){
  float x3 = x * x * x;
  float u2 = 1.5957691216057308f * (x + 0.044715f * x3);   // 2u
  return __fdividef(x, 1.0f + __expf(-u2));
}

// async global->LDS, 16B per lane; LDS dest = wave-uniform base + lane*16
typedef __attribute__((address_space(1))) const u32 gu32;
typedef __attribute__((address_space(3))) u32 lu32;
__device__ __forceinline__ void gload_lds16(const void* g, void* l){
  gu32* gp = (gu32*)(unsigned long long)(uintptr_t)g;
  lu32* lp = (lu32*)(u32)(uintptr_t)l;
  __builtin_amdgcn_global_load_lds(gp, lp, 16, 0, 0);
}

// ---------------- merged prep: cast x + 4 weight transposes, one launch ----------------
__device__ __forceinline__ void transpose_tile(const float* __restrict__ src,
    u16* __restrict__ dst, int R, int C, int bx, int by, int bz,
    float (*tile)[65]){
  const int c0 = bx * 64, r0 = by * 64;
  const size_t bb = (size_t)bz * R * C;
  const int tid = threadIdx.x;
  const int tr = tid >> 4, tc = (tid & 15) * 4;
#pragma unroll
  for (int i = 0; i < 4; i++){
    float4 v = *(const float4*)&src[bb + (size_t)(r0 + tr + i * 16) * C + c0 + tc];
    tile[tr + i * 16][tc + 0] = v.x;
    tile[tr + i * 16][tc + 1] = v.y;
    tile[tr + i * 16][tc + 2] = v.z;
    tile[tr + i * 16][tc + 3] = v.w;
  }
  __syncthreads();
#pragma unroll
  for (int i = 0; i < 4; i++){
    int dr = tr + i * 16;
    ushort4 o;
    o.x = f2bf(tile[tc + 0][dr]);
    o.y = f2bf(tile[tc + 1][dr]);
    o.z = f2bf(tile[tc + 2][dr]);
    o.w = f2bf(tile[tc + 3][dr]);
    *(ushort4*)&dst[bb + (size_t)(c0 + dr) * R + r0 + tc] = o;
  }
}

#define NB_CAST  8192
#define NB_W1    8192
#define NB_W2    8192
#define NB_WS    256

__global__ __launch_bounds__(256) void prep_kernel(
    const float* __restrict__ x, u16* __restrict__ xbf,
    const float* __restrict__ w1, u16* __restrict__ w1T,
    const float* __restrict__ w2, u16* __restrict__ w2T,
    const float* __restrict__ ws1, u16* __restrict__ ws1T,
    const float* __restrict__ ws2, u16* __restrict__ ws2T){
  __shared__ float tile[64][65];
  int b = blockIdx.x;
  if (b < NB_CAST){
    size_t i = ((size_t)b * 256 + threadIdx.x) * 4;
    float4 v = *(const float4*)&x[i];
    ushort4 o;
    o.x = f2bf(v.x); o.y = f2bf(v.y); o.z = f2bf(v.z); o.w = f2bf(v.w);
    *(ushort4*)&xbf[i] = o;
    return;
  }
  b -= NB_CAST;
  if (b < NB_W1){                       // w1 [e][1024][512] -> [e][512][1024]
    int bz = b >> 7, rem = b & 127;
    transpose_tile(w1, w1T, HD, FD, rem & 7, rem >> 3, bz, tile);
    return;
  }
  b -= NB_W1;
  if (b < NB_W2){                       // w2 [e][512][1024] -> [e][1024][512]
    int bz = b >> 7, rem = b & 127;
    transpose_tile(w2, w2T, FD, HD, rem & 15, rem >> 4, bz, tile);
    return;
  }
  b -= NB_W2;
  if (b < NB_WS){                       // ws1 [1024][1024] -> T
    transpose_tile(ws1, ws1T, HD, SFD, b & 15, b >> 4, 0, tile);
    return;
  }
  b -= NB_WS;
  transpose_tile(ws2, ws2T, SFD, HD, b & 15, b >> 4, 0, tile);
}

// ---------------- router GEMM (fp32, deterministic K-split partials) ----------------
__global__ __launch_bounds__(256) void router_gemm(const float* __restrict__ X,
                                                   const float* __restrict__ Wr,
                                                   float* __restrict__ part){
  __shared__ float Xs[32][36];
  __shared__ float Ws[32][64];
  const int t0 = blockIdx.x * 32;
  const int kh = blockIdx.y;
  const int tid = threadIdx.x;
  const int tx = tid & 15, ty = tid >> 4;
  float acc[2][4] = {};
  for (int k0 = kh * 512; k0 < kh * 512 + 512; k0 += 32){
    {
      int c = tid; int r = c >> 3, cc = (c & 7) * 4;
      *(float4*)&Xs[r][cc] = *(const float4*)&X[(size_t)(t0 + r) * HD + k0 + cc];
    }
#pragma unroll
    for (int i = 0; i < 2; i++){
      int c = tid + i * 256; int r = c >> 4, cc = (c & 15) * 4;
      *(float4*)&Ws[r][cc] = *(const float4*)&Wr[(size_t)(k0 + r) * NE + cc];
    }
    __syncthreads();
#pragma unroll
    for (int kk = 0; kk < 32; kk += 4){
      float a[2][4], b[4][4];
#pragma unroll
      for (int i = 0; i < 2; i++){
        float4 v = *(const float4*)&Xs[ty * 2 + i][kk];
        a[i][0] = v.x; a[i][1] = v.y; a[i][2] = v.z; a[i][3] = v.w;
      }
#pragma unroll
      for (int q = 0; q < 4; q++){
        float4 v = *(const float4*)&Ws[kk + q][tx * 4];
        b[q][0] = v.x; b[q][1] = v.y; b[q][2] = v.z; b[q][3] = v.w;
      }
#pragma unroll
      for (int i = 0; i < 2; i++)
#pragma unroll
        for (int j = 0; j < 4; j++)
          acc[i][j] += a[i][0]*b[0][j] + a[i][1]*b[1][j] + a[i][2]*b[2][j] + a[i][3]*b[3][j];
    }
    __syncthreads();
  }
#pragma unroll
  for (int i = 0; i < 2; i++){
    float4 o; o.x = acc[i][0]; o.y = acc[i][1]; o.z = acc[i][2]; o.w = acc[i][3];
    *(float4*)&part[(size_t)kh * TK * NE + (size_t)(t0 + ty * 2 + i) * NE + tx * 4] = o;
  }
}

// ---------------- routing: 32 tokens/block, LDS histogram, 1 global atomic per (block,expert) ----------------
__global__ __launch_bounds__(256) void route_kernel(const float* __restrict__ lp,
    int* __restrict__ cnt, float* __restrict__ Ppart,
    int* __restrict__ assign_row, float* __restrict__ gateA, int* __restrict__ destA,
    u16* __restrict__ Ybuf){
  const int wave = threadIdx.x >> 6, l = threadIdx.x & 63;
  const int tid = threadIdx.x;
  __shared__ int lhist[64];
  __shared__ int s_e[64];
  __shared__ int s_lpos[64];
  __shared__ float s_p[64];
  __shared__ float s_ps[4][64];
  __shared__ int s_base[64];
  if (tid < 64) lhist[tid] = 0;
  __syncthreads();

  const int t0 = blockIdx.x * 32 + wave * 8;
  float psum = 0.f;
  float va = lp[(size_t)t0 * NE + l];
  float vb = lp[(size_t)TK * NE + (size_t)t0 * NE + l];
  for (int i = 0; i < 8; i++){
    float v = va + vb;
    if (i < 7){
      va = lp[(size_t)(t0 + i + 1) * NE + l];
      vb = lp[(size_t)TK * NE + (size_t)(t0 + i + 1) * NE + l];
    }
    float m = v;
#pragma unroll
    for (int s = 32; s; s >>= 1){ float o = __shfl_xor(m, s); m = (o > m) ? o : m; }
    float ex = __expf(v - m);
    float ssum = ex;
#pragma unroll
    for (int s = 32; s; s >>= 1) ssum += __shfl_xor(ssum, s);
    float p = ex / ssum;
    psum += p;
    float bv = p; int bi = l;
#pragma unroll
    for (int s = 32; s; s >>= 1){
      float ov = __shfl_xor(bv, s); int oi = __shfl_xor(bi, s);
      if (ov > bv || (ov == bv && oi < bi)){ bv = ov; bi = oi; }
    }
    int e1 = bi; float p1 = bv;
    float pmask = (l == e1) ? -1.f : p;
    bv = pmask; bi = l;
#pragma unroll
    for (int s = 32; s; s >>= 1){
      float ov = __shfl_xor(bv, s); int oi = __shfl_xor(bi, s);
      if (ov > bv || (ov == bv && oi < bi)){ bv = ov; bi = oi; }
    }
    int e2 = bi; float p2 = bv;
    if (l == 0){
      int lp1 = atomicAdd(&lhist[e1], 1);
      int lp2 = atomicAdd(&lhist[e2], 1);
      int aid = (wave * 8 + i) * 2;
      s_e[aid] = e1; s_lpos[aid] = lp1; s_p[aid] = p1;
      s_e[aid + 1] = e2; s_lpos[aid + 1] = lp2; s_p[aid + 1] = p2;
    }
  }
  s_ps[wave][l] = psum;
  __syncthreads();
  if (tid < 64)
    s_base[tid] = atomicAdd(&cnt[tid * CNTS], lhist[tid]);
  if (wave == 0)
    Ppart[(size_t)blockIdx.x * 64 + l] = s_ps[0][l] + s_ps[1][l] + s_ps[2][l] + s_ps[3][l];
  __syncthreads();
  if (tid < 64){
    int aid = tid;
    int e = s_e[aid];
    int pos = s_base[e] + s_lpos[aid];
    int t = blockIdx.x * 32 + (aid >> 1);
    int dest = 2 * t + (aid & 1);
    if (pos < CAP){
      int s1 = e * CAP + pos;
      assign_row[s1] = t; gateA[s1] = s_p[aid]; destA[s1] = dest;
    } else {
      for (int j = 0; j < HD; j += 8){
        bf16x8 z = {0,0,0,0,0,0,0,0};
        *(bf16x8*)&Ybuf[(size_t)dest * HD + j] = z;
      }
    }
  }
}

// ---------------- pipelined MFMA GEMM core: 128x128 tile, BK=32,
// 3-buffer LDS, 2-deep prefetch, counted vmcnt, XOR-swizzled LDS ----------------
// Swizzle: LDS[r][q16] holds global[r][q16 ^ ((r>>1)&3)] (16B units, 4/row).
// Stage side: permute the per-lane GLOBAL source unit (gload_lds dest must stay linear);
// read side: XOR the frag address with the same involution. 8-way -> 2-way (free) conflicts.
template<int MODE, int KDIM, int NDIM>
__device__ __forceinline__ void gemm_core(
    u16* SMEM,
    const u16* __restrict__ A, const u16* __restrict__ BT,
    u16* __restrict__ Obuf, float* __restrict__ outF,
    int e, int mbase, int nbase, int count,
    const int* __restrict__ assign_row, const float* __restrict__ gate,
    const int* __restrict__ destIdx, const u16* __restrict__ Ybuf)
{
  const int tid = threadIdx.x;
  const int wave = tid >> 6, lane = tid & 63;
  const int wr = wave & 1, wc = wave >> 1;
  const int lm = lane & 15, quad = lane >> 4;
  const int l4r = lane >> 2;
  const int l4c = ((lane & 3) ^ ((lane >> 3) & 3)) * 8;   // swizzled source 16B-unit

  const size_t eoffB = (MODE == M_EXP1 || MODE == M_EXP2) ? (size_t)e * (size_t)NDIM * KDIM : 0;
  const u16* agp[2]; const u16* bgp[2];
  int aoff[2], boff[2];
#pragma unroll
  for (int it = 0; it < 2; it++){
    int ar = wave * 16 + it * 64 + l4r;
    if (MODE == M_EXP1){
      int r = mbase + ar;
      int tok = (r < count) ? assign_row[e * CAP + r] : 0;
      agp[it] = A + (size_t)tok * KDIM + l4c;
    } else if (MODE == M_EXP2){
      agp[it] = A + ((size_t)e * CAP + mbase + ar) * KDIM + l4c;
    } else {
      agp[it] = A + (size_t)(mbase + ar) * KDIM + l4c;
    }
    bgp[it] = BT + eoffB + (size_t)(nbase + ar) * KDIM + l4c;
    aoff[it] = (wave * 16 + it * 64) * 32;
    boff[it] = 4096 + (wave * 16 + it * 64) * 32;
  }

  auto STAGE = [&](int t, int buf){
    const int ko = t * 32;
    u16* base = SMEM + buf * 8192;
    gload_lds16(agp[0] + ko, base + aoff[0]);
    gload_lds16(agp[1] + ko, base + aoff[1]);
    gload_lds16(bgp[0] + ko, base + boff[0]);
    gload_lds16(bgp[1] + ko, base + boff[1]);
  };

  f32x4 acc[4][4];
#pragma unroll
  for (int mi = 0; mi < 4; mi++)
#pragma unroll
    for (int ni = 0; ni < 4; ni++)
      acc[mi][ni] = (f32x4){0.f, 0.f, 0.f, 0.f};

  constexpr int NT = KDIM / 32;
  STAGE(0, 0);
  STAGE(1, 1);
  asm volatile("s_waitcnt vmcnt(4)" ::: "memory");   // buf0 ready, buf1 in flight
  __builtin_amdgcn_s_barrier();
  asm volatile("" ::: "memory");

  const int qs = (quad ^ ((lm >> 1) & 3)) * 8;       // swizzled read unit (row-derived XOR)
  int cur = 0;
  for (int t = 0; t < NT; ++t){
    if (t + 2 < NT){
      int nb = cur + 2; if (nb >= 3) nb -= 3;
      STAGE(t + 2, nb);
    }
    const u16* As_ = SMEM + cur * 8192;
    const u16* Bs_ = As_ + 4096;
    bf16x8 af[4], bfr[4];
#pragma unroll
    for (int mi = 0; mi < 4; mi++)
      af[mi] = *(const bf16x8*)&As_[(wr * 64 + mi * 16 + lm) * 32 + qs];
#pragma unroll
    for (int ni = 0; ni < 4; ni++)
      bfr[ni] = *(const bf16x8*)&Bs_[(wc * 64 + ni * 16 + lm) * 32 + qs];
    // no forced lgkmcnt(0): loads are compiler-visible, backend emits fine-grained waits
    __builtin_amdgcn_s_setprio(1);
#pragma unroll
    for (int mi = 0; mi < 4; mi++)
#pragma unroll
      for (int ni = 0; ni < 4; ni++)
        acc[mi][ni] = __builtin_amdgcn_mfma_f32_16x16x32_bf16(af[mi], bfr[ni], acc[mi][ni], 0, 0, 0);
    __builtin_amdgcn_s_setprio(0);
    if (t + 1 < NT){
      if (t + 2 < NT)
        asm volatile("s_waitcnt vmcnt(4)" ::: "memory");
      else
        asm volatile("s_waitcnt vmcnt(0)" ::: "memory");
      __builtin_amdgcn_s_barrier();
      asm volatile("" ::: "memory");
      cur = cur + 1; if (cur >= 3) cur = 0;
    }
  }

#pragma unroll
  for (int mi = 0; mi < 4; mi++){
#pragma unroll
    for (int i = 0; i < 4; i++){
      int r = mbase + wr * 64 + mi * 16 + quad * 4 + i;
      if ((MODE == M_EXP1 || MODE == M_EXP2) && r >= count) continue;
      u16* brow = nullptr;
      float* orow = nullptr;
      const u16 *yb0 = nullptr, *yb1 = nullptr;
      float g = 0.f;
      if (MODE == M_EXP1){
        brow = Obuf + ((size_t)e * CAP + r) * NDIM;
      } else if (MODE == M_EXP2){
        int d = destIdx[e * CAP + r];
        g = gate[e * CAP + r];
        brow = Obuf + (size_t)d * NDIM;
      } else if (MODE == M_SH1){
        brow = Obuf + (size_t)r * NDIM;
      } else {
        orow = outF + (size_t)r * NDIM;
        yb0 = Ybuf + (size_t)(2 * r) * NDIM;
        yb1 = Ybuf + (size_t)(2 * r + 1) * NDIM;
      }
#pragma unroll
      for (int ni = 0; ni < 4; ni++){
        int c = nbase + wc * 64 + ni * 16 + lm;
        float v = acc[mi][ni][i];
        if (MODE == M_EXP1)      brow[c] = f2bf(gelu_tanh(v));
        else if (MODE == M_EXP2) brow[c] = f2bf(g * v);
        else if (MODE == M_SH1)  brow[c] = f2bf(gelu_tanh(v));
        else                     orow[c] = v + bf2f(yb0[c]) + bf2f(yb1[c]);
      }
    }
  }
}

// ---------------- phase A: EXP1 (2048 blocks) + SH1 (512 blocks), fused ----------------
__global__ __launch_bounds__(256) void gemm_phaseA(
    const u16* __restrict__ xbf, const u16* __restrict__ w1T, const u16* __restrict__ ws1T,
    u16* __restrict__ Hbuf, u16* __restrict__ Shb,
    const int* __restrict__ cnt, const int* __restrict__ assign_row)
{
  __shared__ __align__(16) u16 SMEM[3 * 8192];
  const int bid = blockIdx.x;
  if (bid < 2048){
    int logical = (bid & 7) * 256 + (bid >> 3);
    int e = logical >> 5, r = logical & 31;
    int mbase = (r >> 2) * 128, nbase = (r & 3) * 128;
    int count = cnt[e * CNTS];
    if (mbase >= count) return;
    gemm_core<M_EXP1, HD, FD>(SMEM, xbf, w1T, Hbuf, nullptr, e, mbase, nbase, count,
                              assign_row, nullptr, nullptr, nullptr);
  } else {
    int b2 = bid - 2048;
    int logical = (b2 & 7) * 64 + (b2 >> 3);
    int mbase = (logical >> 3) * 128, nbase = (logical & 7) * 128;
    gemm_core<M_SH1, HD, SFD>(SMEM, xbf, ws1T, Shb, nullptr, 0, mbase, nbase, 0,
                              nullptr, nullptr, nullptr, nullptr);
  }
}

// ---------------- phase B: EXP2 (4096 blocks) ----------------
__global__ __launch_bounds__(256) void gemm_exp2(
    const u16* __restrict__ Hbuf, const u16* __restrict__ w2T, u16* __restrict__ Ybuf,
    const int* __restrict__ cnt, const float* __restrict__ gateA, const int* __restrict__ destA)
{
  __shared__ __align__(16) u16 SMEM[3 * 8192];
  const int bid = blockIdx.x;
  int logical = (bid & 7) * 512 + (bid >> 3);
  int e = logical >> 6, r = logical & 63;
  int mbase = (r >> 3) * 128, nbase = (r & 7) * 128;
  int count = cnt[e * CNTS];
  if (mbase >= count) return;
  gemm_core<M_EXP2, FD, HD>(SMEM, Hbuf, w2T, Ybuf, nullptr, e, mbase, nbase, count,
                            nullptr, gateA, destA, nullptr);
}

// ---------------- phase C: SH2 + combine (512 blocks) ----------------
__global__ __launch_bounds__(256) void gemm_sh2(
    const u16* __restrict__ Shb, const u16* __restrict__ ws2T,
    float* __restrict__ outF, const u16* __restrict__ Ybuf)
{
  __shared__ __align__(16) u16 SMEM[3 * 8192];
  const int bid = blockIdx.x;
  int logical = (bid & 7) * 64 + (bid >> 3);
  int mbase = (logical >> 3) * 128, nbase = (logical & 7) * 128;
  gemm_core<M_SH2, SFD, HD>(SMEM, Shb, ws2T, nullptr, outF, 0, mbase, nbase, 0,
                            nullptr, nullptr, nullptr, Ybuf);
}

// ---------------- aux: reduce Ppart[256][64] + cnt -> loss ----------------
__global__ __launch_bounds__(256) void aux_kernel(const int* __restrict__ cnt,
    const float* __restrict__ Ppart, float* __restrict__ out){
  const int l = threadIdx.x & 63, w = threadIdx.x >> 6;
  float s = 0.f;
#pragma unroll 4
  for (int j = 0; j < 64; j++)
    s += Ppart[(size_t)(w + 4 * j) * 64 + l];
  __shared__ float sh[4][64];
  sh[w][l] = s;
  __syncthreads();
  if (w == 0){
    float P = (sh[0][l] + sh[1][l] + sh[2][l] + sh[3][l]) * (1.0f / (float)TK);
    float f = (float)cnt[l * CNTS] * (1.0f / (float)(TK * TOPK));
    float v = f * P;
#pragma unroll
    for (int s2 = 32; s2; s2 >>= 1) v += __shfl_xor(v, s2);
    if (l == 0) out[(size_t)TK * HD] = 0.64f * v;   // COEFF * E = 0.01 * 64
  }
}

extern "C" void kernel_launch(void* const* d_in, const int* in_sizes, int n_in,
                              void* d_out, int out_size, void* d_ws, size_t ws_size,
                              hipStream_t stream){
  const float* x   = (const float*)d_in[0];
  const float* wr  = (const float*)d_in[1];
  const float* w1  = (const float*)d_in[2];
  const float* w2  = (const float*)d_in[3];
  const float* ws1 = (const float*)d_in[4];
  const float* ws2 = (const float*)d_in[5];
  float* out = (float*)d_out;

  char* W = (char*)d_ws;
  size_t off = 0;
  auto alloc = [&](size_t b){ size_t o = off; off = (off + b + 255) & ~(size_t)255; return o; };
  u16*   xbf   = (u16*)(W + alloc((size_t)TK * HD * 2));
  u16*   w1T   = (u16*)(W + alloc((size_t)NE * FD * HD * 2));
  u16*   w2T   = (u16*)(W + alloc((size_t)NE * HD * FD * 2));
  u16*   ws1T  = (u16*)(W + alloc((size_t)HD * SFD * 2));
  u16*   ws2T  = (u16*)(W + alloc((size_t)SFD * HD * 2));
  u16*   Hbuf  = (u16*)(W + alloc((size_t)NE * CAP * FD * 2));
  u16*   Shb   = (u16*)(W + alloc((size_t)TK * SFD * 2));
  u16*   Ybuf  = (u16*)(W + alloc((size_t)TK * TOPK * HD * 2));
  float* lpart = (float*)(W + alloc((size_t)2 * TK * NE * 4));
  int*   assign_row = (int*)(W + alloc((size_t)NE * CAP * 4));
  float* gateA = (float*)(W + alloc((size_t)NE * CAP * 4));
  int*   destA = (int*)(W + alloc((size_t)NE * CAP * 4));
  float* Ppart = (float*)(W + alloc((size_t)256 * 64 * 4));
  int*   cnt   = (int*)(W + alloc((size_t)NE * CNTS * 4));

  hipMemsetAsync(cnt, 0, (size_t)NE * CNTS * 4, stream);

  prep_kernel<<<dim3(NB_CAST + NB_W1 + NB_W2 + 2 * NB_WS), 256, 0, stream>>>(
      x, xbf, w1, w1T, w2, w2T, ws1, ws1T, ws2, ws2T);

  router_gemm<<<dim3(TK / 32, 2), 256, 0, stream>>>(x, wr, lpart);
  route_kernel<<<dim3(TK / 32), 256, 0, stream>>>(lpart, cnt, Ppart, assign_row, gateA, destA, Ybuf);

  gemm_phaseA<<<dim3(2048 + 512), 256, 0, stream>>>(xbf, w1T, ws1T, Hbuf, Shb, cnt, assign_row);
  gemm_exp2<<<dim3(4096), 256, 0, stream>>>(Hbuf, w2T, Ybuf, cnt, gateA, destA);
  gemm_sh2<<<dim3(512), 256, 0, stream>>>(Shb, ws2T, out, Ybuf);

  aux_kernel<<<dim3(1), 256, 0, stream>>>(cnt, Ppart, out);
}

// Round 4
// 505.528 us; speedup vs baseline: 1.4312x; 1.0389x over previous
//
#include <hip/hip_runtime.h>
#include <hip/hip_bf16.h>

#define TK 8192
#define HD 1024
#define NE 64
#define TOPK 2
#define CAP 1024
#define FD 512
#define SFD 1024
#define CNTS 32   // cnt stride in ints -> 128B per expert counter (one cache line each)

typedef unsigned short u16;
typedef unsigned int u32;
typedef short bf16x8 __attribute__((ext_vector_type(8)));
typedef float f32x4 __attribute__((ext_vector_type(4)));
typedef u16 u16x8 __attribute__((ext_vector_type(8)));

#define M_EXP1 0
#define M_EXP2 1
#define M_SH1  2
#define M_SH2  3

__device__ __forceinline__ float bf2f(u16 b){
  u32 u = ((u32)b) << 16;
  return __uint_as_float(u);
}
__device__ __forceinline__ u16 f2bf(float f){
  u32 u = __float_as_uint(f);
  u32 r = (u + 0x7fffu + ((u >> 16) & 1u)) >> 16;
  return (u16)r;
}
// gelu tanh-approx: 0.5x(1+tanh(u)) == x * sigmoid(2u), u = 0.79788456*(x+0.044715x^3)
__device__ __forceinline__ float gelu_tanh(float x){
  float x3 = x * x * x;
  float u2 = 1.5957691216057308f * (x + 0.044715f * x3);   // 2u
  return __fdividef(x, 1.0f + __expf(-u2));
}

// async global->LDS, 16B per lane; LDS dest = wave-uniform base + lane*16
typedef __attribute__((address_space(1))) const u32 gu32;
typedef __attribute__((address_space(3))) u32 lu32;
__device__ __forceinline__ void gload_lds16(const void* g, void* l){
  gu32* gp = (gu32*)(unsigned long long)(uintptr_t)g;
  lu32* lp = (lu32*)(u32)(uintptr_t)l;
  __builtin_amdgcn_global_load_lds(gp, lp, 16, 0, 0);
}

// ---------------- transpose tile: fp32 [R][C] tile -> bf16 [C][R], 16B stores ----------------
__device__ __forceinline__ void transpose_tile(const float* __restrict__ src,
    u16* __restrict__ dst, int R, int C, int bx, int by, int bz,
    float (*tile)[65]){
  const int c0 = bx * 64, r0 = by * 64;
  const size_t bb = (size_t)bz * R * C;
  const int tid = threadIdx.x;
  const int tr = tid >> 4, tc = (tid & 15) * 4;
#pragma unroll
  for (int i = 0; i < 4; i++){
    float4 v = *(const float4*)&src[bb + (size_t)(r0 + tr + i * 16) * C + c0 + tc];
    tile[tr + i * 16][tc + 0] = v.x;
    tile[tr + i * 16][tc + 1] = v.y;
    tile[tr + i * 16][tc + 2] = v.z;
    tile[tr + i * 16][tc + 3] = v.w;
  }
  __syncthreads();
  // write: each thread emits 2x u16x8 (16B). bank ~ 8m+j+q -> 2-way (free).
  const int wrow = tid >> 3;        // 0..31
  const int wcol = (tid & 7) * 8;   // 0..56
#pragma unroll
  for (int i = 0; i < 2; i++){
    int dr = wrow + i * 32;
    u16x8 o;
#pragma unroll
    for (int j = 0; j < 8; j++)
      o[j] = f2bf(tile[wcol + j][dr]);
    *(u16x8*)&dst[bb + (size_t)(c0 + dr) * R + r0 + wcol] = o;
  }
}

// ---------------- router GEMM body (fp32, deterministic K-split partials) ----------------
__device__ __forceinline__ void router_body(const float* __restrict__ X,
    const float* __restrict__ Wr, float* __restrict__ part,
    int bx, int kh, char* smem){
  float (*Xs)[36] = (float(*)[36])smem;
  float (*Ws)[64] = (float(*)[64])(smem + 32 * 36 * 4);
  const int t0 = bx * 32;
  const int tid = threadIdx.x;
  const int tx = tid & 15, ty = tid >> 4;
  float acc[2][4] = {};
  for (int k0 = kh * 512; k0 < kh * 512 + 512; k0 += 32){
    {
      int c = tid; int r = c >> 3, cc = (c & 7) * 4;
      *(float4*)&Xs[r][cc] = *(const float4*)&X[(size_t)(t0 + r) * HD + k0 + cc];
    }
#pragma unroll
    for (int i = 0; i < 2; i++){
      int c = tid + i * 256; int r = c >> 4, cc = (c & 15) * 4;
      *(float4*)&Ws[r][cc] = *(const float4*)&Wr[(size_t)(k0 + r) * NE + cc];
    }
    __syncthreads();
#pragma unroll
    for (int kk = 0; kk < 32; kk += 4){
      float a[2][4], b[4][4];
#pragma unroll
      for (int i = 0; i < 2; i++){
        float4 v = *(const float4*)&Xs[ty * 2 + i][kk];
        a[i][0] = v.x; a[i][1] = v.y; a[i][2] = v.z; a[i][3] = v.w;
      }
#pragma unroll
      for (int q = 0; q < 4; q++){
        float4 v = *(const float4*)&Ws[kk + q][tx * 4];
        b[q][0] = v.x; b[q][1] = v.y; b[q][2] = v.z; b[q][3] = v.w;
      }
#pragma unroll
      for (int i = 0; i < 2; i++)
#pragma unroll
        for (int j = 0; j < 4; j++)
          acc[i][j] += a[i][0]*b[0][j] + a[i][1]*b[1][j] + a[i][2]*b[2][j] + a[i][3]*b[3][j];
    }
    __syncthreads();
  }
#pragma unroll
  for (int i = 0; i < 2; i++){
    float4 o; o.x = acc[i][0]; o.y = acc[i][1]; o.z = acc[i][2]; o.w = acc[i][3];
    *(float4*)&part[(size_t)kh * TK * NE + (size_t)(t0 + ty * 2 + i) * NE + tx * 4] = o;
  }
}

// ---------------- merged prep: router + cast x + 4 weight transposes, one launch ----------------
#define NB_RT    512
#define NB_CAST  8192
#define NB_W1    8192
#define NB_W2    8192
#define NB_WS    256

__global__ __launch_bounds__(256) void prep_kernel(
    const float* __restrict__ x, u16* __restrict__ xbf,
    const float* __restrict__ w1, u16* __restrict__ w1T,
    const float* __restrict__ w2, u16* __restrict__ w2T,
    const float* __restrict__ ws1, u16* __restrict__ ws1T,
    const float* __restrict__ ws2, u16* __restrict__ ws2T,
    const float* __restrict__ wr, float* __restrict__ lpart){
  __shared__ __align__(16) char smem[64 * 65 * 4];
  float (*tile)[65] = (float(*)[65])smem;
  int b = blockIdx.x;
  if (b < NB_RT){                       // router first: finishes early, hides under streaming
    router_body(x, wr, lpart, b >> 1, b & 1, smem);
    return;
  }
  b -= NB_RT;
  if (b < NB_CAST){
    size_t i = ((size_t)b * 256 + threadIdx.x) * 4;
    float4 v = *(const float4*)&x[i];
    ushort4 o;
    o.x = f2bf(v.x); o.y = f2bf(v.y); o.z = f2bf(v.z); o.w = f2bf(v.w);
    *(ushort4*)&xbf[i] = o;
    return;
  }
  b -= NB_CAST;
  if (b < NB_W1){                       // w1 [e][1024][512] -> [e][512][1024]
    int bz = b >> 7, rem = b & 127;
    transpose_tile(w1, w1T, HD, FD, rem & 7, rem >> 3, bz, tile);
    return;
  }
  b -= NB_W1;
  if (b < NB_W2){                       // w2 [e][512][1024] -> [e][1024][512]
    int bz = b >> 7, rem = b & 127;
    transpose_tile(w2, w2T, FD, HD, rem & 15, rem >> 4, bz, tile);
    return;
  }
  b -= NB_W2;
  if (b < NB_WS){                       // ws1 [1024][1024] -> T
    transpose_tile(ws1, ws1T, HD, SFD, b & 15, b >> 4, 0, tile);
    return;
  }
  b -= NB_WS;
  transpose_tile(ws2, ws2T, SFD, HD, b & 15, b >> 4, 0, tile);
}

// ---------------- routing: 32 tokens/block, LDS histogram, 1 global atomic per (block,expert) ----------------
__global__ __launch_bounds__(256) void route_kernel(const float* __restrict__ lp,
    int* __restrict__ cnt, float* __restrict__ Ppart,
    int* __restrict__ assign_row, float* __restrict__ gateA, int* __restrict__ destA,
    u16* __restrict__ Ybuf){
  const int wave = threadIdx.x >> 6, l = threadIdx.x & 63;
  const int tid = threadIdx.x;
  __shared__ int lhist[64];
  __shared__ int s_e[64];
  __shared__ int s_lpos[64];
  __shared__ float s_p[64];
  __shared__ float s_ps[4][64];
  __shared__ int s_base[64];
  if (tid < 64) lhist[tid] = 0;
  __syncthreads();

  const int t0 = blockIdx.x * 32 + wave * 8;
  float psum = 0.f;
  float va = lp[(size_t)t0 * NE + l];
  float vb = lp[(size_t)TK * NE + (size_t)t0 * NE + l];
  for (int i = 0; i < 8; i++){
    float v = va + vb;
    if (i < 7){
      va = lp[(size_t)(t0 + i + 1) * NE + l];
      vb = lp[(size_t)TK * NE + (size_t)(t0 + i + 1) * NE + l];
    }
    float m = v;
#pragma unroll
    for (int s = 32; s; s >>= 1){ float o = __shfl_xor(m, s); m = (o > m) ? o : m; }
    float ex = __expf(v - m);
    float ssum = ex;
#pragma unroll
    for (int s = 32; s; s >>= 1) ssum += __shfl_xor(ssum, s);
    float p = ex / ssum;
    psum += p;
    float bv = p; int bi = l;
#pragma unroll
    for (int s = 32; s; s >>= 1){
      float ov = __shfl_xor(bv, s); int oi = __shfl_xor(bi, s);
      if (ov > bv || (ov == bv && oi < bi)){ bv = ov; bi = oi; }
    }
    int e1 = bi; float p1 = bv;
    float pmask = (l == e1) ? -1.f : p;
    bv = pmask; bi = l;
#pragma unroll
    for (int s = 32; s; s >>= 1){
      float ov = __shfl_xor(bv, s); int oi = __shfl_xor(bi, s);
      if (ov > bv || (ov == bv && oi < bi)){ bv = ov; bi = oi; }
    }
    int e2 = bi; float p2 = bv;
    if (l == 0){
      int lp1 = atomicAdd(&lhist[e1], 1);
      int lp2 = atomicAdd(&lhist[e2], 1);
      int aid = (wave * 8 + i) * 2;
      s_e[aid] = e1; s_lpos[aid] = lp1; s_p[aid] = p1;
      s_e[aid + 1] = e2; s_lpos[aid + 1] = lp2; s_p[aid + 1] = p2;
    }
  }
  s_ps[wave][l] = psum;
  __syncthreads();
  if (tid < 64)
    s_base[tid] = atomicAdd(&cnt[tid * CNTS], lhist[tid]);
  if (wave == 0)
    Ppart[(size_t)blockIdx.x * 64 + l] = s_ps[0][l] + s_ps[1][l] + s_ps[2][l] + s_ps[3][l];
  __syncthreads();
  if (tid < 64){
    int aid = tid;
    int e = s_e[aid];
    int pos = s_base[e] + s_lpos[aid];
    int t = blockIdx.x * 32 + (aid >> 1);
    int dest = 2 * t + (aid & 1);
    if (pos < CAP){
      int s1 = e * CAP + pos;
      assign_row[s1] = t; gateA[s1] = s_p[aid]; destA[s1] = dest;
    } else {
      for (int j = 0; j < HD; j += 8){
        bf16x8 z = {0,0,0,0,0,0,0,0};
        *(bf16x8*)&Ybuf[(size_t)dest * HD + j] = z;
      }
    }
  }
}

// ---------------- pipelined MFMA GEMM core: 128x128 tile, BK=32,
// 3-buffer LDS, 2-deep prefetch, counted vmcnt, XOR-swizzled LDS ----------------
template<int MODE, int KDIM, int NDIM>
__device__ __forceinline__ void gemm_core(
    u16* SMEM,
    const u16* __restrict__ A, const u16* __restrict__ BT,
    u16* __restrict__ Obuf, float* __restrict__ outF,
    int e, int mbase, int nbase, int count,
    const int* __restrict__ assign_row, const float* __restrict__ gate,
    const int* __restrict__ destIdx, const u16* __restrict__ Ybuf)
{
  const int tid = threadIdx.x;
  const int wave = tid >> 6, lane = tid & 63;
  const int wr = wave & 1, wc = wave >> 1;
  const int lm = lane & 15, quad = lane >> 4;
  const int l4r = lane >> 2;
  const int l4c = ((lane & 3) ^ ((lane >> 3) & 3)) * 8;   // swizzled source 16B-unit

  const size_t eoffB = (MODE == M_EXP1 || MODE == M_EXP2) ? (size_t)e * (size_t)NDIM * KDIM : 0;
  const u16* agp[2]; const u16* bgp[2];
  int aoff[2], boff[2];
#pragma unroll
  for (int it = 0; it < 2; it++){
    int ar = wave * 16 + it * 64 + l4r;
    if (MODE == M_EXP1){
      int r = mbase + ar;
      int tok = (r < count) ? assign_row[e * CAP + r] : 0;
      agp[it] = A + (size_t)tok * KDIM + l4c;
    } else if (MODE == M_EXP2){
      agp[it] = A + ((size_t)e * CAP + mbase + ar) * KDIM + l4c;
    } else {
      agp[it] = A + (size_t)(mbase + ar) * KDIM + l4c;
    }
    bgp[it] = BT + eoffB + (size_t)(nbase + ar) * KDIM + l4c;
    aoff[it] = (wave * 16 + it * 64) * 32;
    boff[it] = 4096 + (wave * 16 + it * 64) * 32;
  }

  auto STAGE = [&](int t, int buf){
    const int ko = t * 32;
    u16* base = SMEM + buf * 8192;
    gload_lds16(agp[0] + ko, base + aoff[0]);
    gload_lds16(agp[1] + ko, base + aoff[1]);
    gload_lds16(bgp[0] + ko, base + boff[0]);
    gload_lds16(bgp[1] + ko, base + boff[1]);
  };

  f32x4 acc[4][4];
#pragma unroll
  for (int mi = 0; mi < 4; mi++)
#pragma unroll
    for (int ni = 0; ni < 4; ni++)
      acc[mi][ni] = (f32x4){0.f, 0.f, 0.f, 0.f};

  constexpr int NT = KDIM / 32;
  STAGE(0, 0);
  STAGE(1, 1);
  asm volatile("s_waitcnt vmcnt(4)" ::: "memory");   // buf0 ready, buf1 in flight
  __builtin_amdgcn_s_barrier();
  asm volatile("" ::: "memory");

  const int qs = (quad ^ ((lm >> 1) & 3)) * 8;       // swizzled read unit (row-derived XOR)
  int cur = 0;
  for (int t = 0; t < NT; ++t){
    if (t + 2 < NT){
      int nb = cur + 2; if (nb >= 3) nb -= 3;
      STAGE(t + 2, nb);
    }
    const u16* As_ = SMEM + cur * 8192;
    const u16* Bs_ = As_ + 4096;
    bf16x8 af[4], bfr[4];
#pragma unroll
    for (int mi = 0; mi < 4; mi++)
      af[mi] = *(const bf16x8*)&As_[(wr * 64 + mi * 16 + lm) * 32 + qs];
#pragma unroll
    for (int ni = 0; ni < 4; ni++)
      bfr[ni] = *(const bf16x8*)&Bs_[(wc * 64 + ni * 16 + lm) * 32 + qs];
    // no forced lgkmcnt(0): loads are compiler-visible, backend emits fine-grained waits
    __builtin_amdgcn_s_setprio(1);
#pragma unroll
    for (int mi = 0; mi < 4; mi++)
#pragma unroll
      for (int ni = 0; ni < 4; ni++)
        acc[mi][ni] = __builtin_amdgcn_mfma_f32_16x16x32_bf16(af[mi], bfr[ni], acc[mi][ni], 0, 0, 0);
    __builtin_amdgcn_s_setprio(0);
    if (t + 1 < NT){
      if (t + 2 < NT)
        asm volatile("s_waitcnt vmcnt(4)" ::: "memory");
      else
        asm volatile("s_waitcnt vmcnt(0)" ::: "memory");
      __builtin_amdgcn_s_barrier();
      asm volatile("" ::: "memory");
      cur = cur + 1; if (cur >= 3) cur = 0;
    }
  }

#pragma unroll
  for (int mi = 0; mi < 4; mi++){
#pragma unroll
    for (int i = 0; i < 4; i++){
      int r = mbase + wr * 64 + mi * 16 + quad * 4 + i;
      if ((MODE == M_EXP1 || MODE == M_EXP2) && r >= count) continue;
      u16* brow = nullptr;
      float* orow = nullptr;
      const u16 *yb0 = nullptr, *yb1 = nullptr;
      float g = 0.f;
      if (MODE == M_EXP1){
        brow = Obuf + ((size_t)e * CAP + r) * NDIM;
      } else if (MODE == M_EXP2){
        int d = destIdx[e * CAP + r];
        g = gate[e * CAP + r];
        brow = Obuf + (size_t)d * NDIM;
      } else if (MODE == M_SH1){
        brow = Obuf + (size_t)r * NDIM;
      } else {
        orow = outF + (size_t)r * NDIM;
        yb0 = Ybuf + (size_t)(2 * r) * NDIM;
        yb1 = Ybuf + (size_t)(2 * r + 1) * NDIM;
      }
#pragma unroll
      for (int ni = 0; ni < 4; ni++){
        int c = nbase + wc * 64 + ni * 16 + lm;
        float v = acc[mi][ni][i];
        if (MODE == M_EXP1)      brow[c] = f2bf(gelu_tanh(v));
        else if (MODE == M_EXP2) brow[c] = f2bf(g * v);
        else if (MODE == M_SH1)  brow[c] = f2bf(gelu_tanh(v));
        else                     orow[c] = v + bf2f(yb0[c]) + bf2f(yb1[c]);
      }
    }
  }
}

// ---------------- phase A: EXP1 (2048) + SH1 (512) + aux (1 block), fused ----------------
__global__ __launch_bounds__(256) void gemm_phaseA(
    const u16* __restrict__ xbf, const u16* __restrict__ w1T, const u16* __restrict__ ws1T,
    u16* __restrict__ Hbuf, u16* __restrict__ Shb,
    const int* __restrict__ cnt, const int* __restrict__ assign_row,
    const float* __restrict__ Ppart, float* __restrict__ outF)
{
  __shared__ __align__(16) u16 SMEM[3 * 8192];
  const int bid = blockIdx.x;
  if (bid < 2048){
    int logical = (bid & 7) * 256 + (bid >> 3);
    int e = logical >> 5, r = logical & 31;
    int mbase = (r >> 2) * 128, nbase = (r & 3) * 128;
    int count = cnt[e * CNTS];
    if (mbase >= count) return;
    gemm_core<M_EXP1, HD, FD>(SMEM, xbf, w1T, Hbuf, nullptr, e, mbase, nbase, count,
                              assign_row, nullptr, nullptr, nullptr);
  } else if (bid < 2560){
    int b2 = bid - 2048;
    int logical = (b2 & 7) * 64 + (b2 >> 3);
    int mbase = (logical >> 3) * 128, nbase = (logical & 7) * 128;
    gemm_core<M_SH1, HD, SFD>(SMEM, xbf, ws1T, Shb, nullptr, 0, mbase, nbase, 0,
                              nullptr, nullptr, nullptr, nullptr);
  } else {
    // aux-loss block: inputs (cnt, Ppart) are complete before this dispatch
    float* shf = (float*)SMEM;
    const int l = threadIdx.x & 63, w = threadIdx.x >> 6;
    float s = 0.f;
#pragma unroll 4
    for (int j = 0; j < 64; j++)
      s += Ppart[(size_t)(w + 4 * j) * 64 + l];
    shf[w * 64 + l] = s;
    __syncthreads();
    if (w == 0){
      float P = (shf[0 * 64 + l] + shf[1 * 64 + l] + shf[2 * 64 + l] + shf[3 * 64 + l]) * (1.0f / (float)TK);
      float f = (float)cnt[l * CNTS] * (1.0f / (float)(TK * TOPK));
      float v = f * P;
#pragma unroll
      for (int s2 = 32; s2; s2 >>= 1) v += __shfl_xor(v, s2);
      if (l == 0) outF[(size_t)TK * HD] = 0.64f * v;   // COEFF * E = 0.01 * 64
    }
  }
}

// ---------------- phase B: EXP2 (4096 blocks) ----------------
__global__ __launch_bounds__(256) void gemm_exp2(
    const u16* __restrict__ Hbuf, const u16* __restrict__ w2T, u16* __restrict__ Ybuf,
    const int* __restrict__ cnt, const float* __restrict__ gateA, const int* __restrict__ destA)
{
  __shared__ __align__(16) u16 SMEM[3 * 8192];
  const int bid = blockIdx.x;
  int logical = (bid & 7) * 512 + (bid >> 3);
  int e = logical >> 6, r = logical & 63;
  int mbase = (r >> 3) * 128, nbase = (r & 7) * 128;
  int count = cnt[e * CNTS];
  if (mbase >= count) return;
  gemm_core<M_EXP2, FD, HD>(SMEM, Hbuf, w2T, Ybuf, nullptr, e, mbase, nbase, count,
                            nullptr, gateA, destA, nullptr);
}

// ---------------- phase C: SH2 + combine (512 blocks) ----------------
__global__ __launch_bounds__(256) void gemm_sh2(
    const u16* __restrict__ Shb, const u16* __restrict__ ws2T,
    float* __restrict__ outF, const u16* __restrict__ Ybuf)
{
  __shared__ __align__(16) u16 SMEM[3 * 8192];
  const int bid = blockIdx.x;
  int logical = (bid & 7) * 64 + (bid >> 3);
  int mbase = (logical >> 3) * 128, nbase = (logical & 7) * 128;
  gemm_core<M_SH2, SFD, HD>(SMEM, Shb, ws2T, nullptr, outF, 0, mbase, nbase, 0,
                            nullptr, nullptr, nullptr, Ybuf);
}

extern "C" void kernel_launch(void* const* d_in, const int* in_sizes, int n_in,
                              void* d_out, int out_size, void* d_ws, size_t ws_size,
                              hipStream_t stream){
  const float* x   = (const float*)d_in[0];
  const float* wr  = (const float*)d_in[1];
  const float* w1  = (const float*)d_in[2];
  const float* w2  = (const float*)d_in[3];
  const float* ws1 = (const float*)d_in[4];
  const float* ws2 = (const float*)d_in[5];
  float* out = (float*)d_out;

  char* W = (char*)d_ws;
  size_t off = 0;
  auto alloc = [&](size_t b){ size_t o = off; off = (off + b + 255) & ~(size_t)255; return o; };
  u16*   xbf   = (u16*)(W + alloc((size_t)TK * HD * 2));
  u16*   w1T   = (u16*)(W + alloc((size_t)NE * FD * HD * 2));
  u16*   w2T   = (u16*)(W + alloc((size_t)NE * HD * FD * 2));
  u16*   ws1T  = (u16*)(W + alloc((size_t)HD * SFD * 2));
  u16*   ws2T  = (u16*)(W + alloc((size_t)SFD * HD * 2));
  u16*   Hbuf  = (u16*)(W + alloc((size_t)NE * CAP * FD * 2));
  u16*   Shb   = (u16*)(W + alloc((size_t)TK * SFD * 2));
  u16*   Ybuf  = (u16*)(W + alloc((size_t)TK * TOPK * HD * 2));
  float* lpart = (float*)(W + alloc((size_t)2 * TK * NE * 4));
  int*   assign_row = (int*)(W + alloc((size_t)NE * CAP * 4));
  float* gateA = (float*)(W + alloc((size_t)NE * CAP * 4));
  int*   destA = (int*)(W + alloc((size_t)NE * CAP * 4));
  float* Ppart = (float*)(W + alloc((size_t)256 * 64 * 4));
  int*   cnt   = (int*)(W + alloc((size_t)NE * CNTS * 4));

  hipMemsetAsync(cnt, 0, (size_t)NE * CNTS * 4, stream);

  prep_kernel<<<dim3(NB_RT + NB_CAST + NB_W1 + NB_W2 + 2 * NB_WS), 256, 0, stream>>>(
      x, xbf, w1, w1T, w2, w2T, ws1, ws1T, ws2, ws2T, wr, lpart);

  route_kernel<<<dim3(TK / 32), 256, 0, stream>>>(lpart, cnt, Ppart, assign_row, gateA, destA, Ybuf);

  gemm_phaseA<<<dim3(2048 + 512 + 1), 256, 0, stream>>>(xbf, w1T, ws1T, Hbuf, Shb, cnt, assign_row, Ppart, out);
  gemm_exp2<<<dim3(4096), 256, 0, stream>>>(Hbuf, w2T, Ybuf, cnt, gateA, destA);
  gemm_sh2<<<dim3(512), 256, 0, stream>>>(Shb, ws2T, out, Ybuf);
}